// Round 16
// baseline (1889.454 us; speedup 1.0000x reference)
//
#include <hip/hip_runtime.h>
#include <cmath>

// ---------------------------------------------------------------------------
// LSTM T=512 B=64 I=512 H=512, fp32 in/out, bf16 MFMA compute.
// v16 = v13 scan + gemm_xproj FUSED into one launch (544 blocks):
//   blocks 0..31  : persistent scan (v13 protocol byte-identical), Xg
//                   consumption gated on per-mt tile counters (flag-ack
//                   pattern, no content validation), Xg read sc0sc1.
//   blocks 32..543: gemm workers, 8 tiles each, mt-ascending order, Xg
//                   stores sc0sc1 + vmcnt ack + syncthreads + xcnt[mt]++.
// The serial ~110us gemm prefix collapses into the scan's idle CUs.
// ---------------------------------------------------------------------------

typedef __attribute__((ext_vector_type(8)))  short   short8;
typedef __attribute__((ext_vector_type(4)))  short   short4v;
typedef __attribute__((ext_vector_type(4)))  float   f32x4;
typedef __attribute__((ext_vector_type(16))) float   f32x16;

#define TSTEPS 512

__device__ __forceinline__ unsigned short f2bf(float f) {
  unsigned u = __builtin_bit_cast(unsigned, f);
  unsigned r = (u + 0x7FFFu + ((u >> 16) & 1u)) >> 16;
  return (unsigned short)r;
}
__device__ __forceinline__ float bf2f(unsigned short s) {
  unsigned u = ((unsigned)s) << 16;
  return __builtin_bit_cast(float, u);
}
__device__ __forceinline__ void gload_lds16(const void* g, void* l) {
  __builtin_amdgcn_global_load_lds(
      (const __attribute__((address_space(1))) unsigned int*)g,
      (__attribute__((address_space(3))) unsigned int*)l, 16, 0, 0);
}
__device__ __forceinline__ float sigmoid_fast(float x) {
  return 1.0f / (1.0f + __expf(-x));
}
__device__ __forceinline__ float tanh_fast(float x) {
  float e = __expf(2.0f * x);
  return 1.0f - 2.0f / (e + 1.0f);
}

// ---------------------------------------------------------------------------
// Prep: transpose+convert weights [512][512] f32 (k-major) -> bf16 [g*512+h][k]
// ---------------------------------------------------------------------------
__global__ __launch_bounds__(256) void prep_wT(
    const float* __restrict__ Wax, const float* __restrict__ Wix,
    const float* __restrict__ Wfx, const float* __restrict__ Wox,
    const float* __restrict__ Wah, const float* __restrict__ Wih,
    const float* __restrict__ Wfh, const float* __restrict__ Woh,
    unsigned short* __restrict__ WxT, unsigned short* __restrict__ WhT) {
  __shared__ float tile[32][33];
  int bx = blockIdx.x;              // 8 mats * 256 tiles
  int mat = bx >> 8;
  int t32 = bx & 255;
  int k0 = (t32 & 15) * 32;
  int h0 = (t32 >> 4) * 32;
  const float* S =
      (mat == 0) ? Wax : (mat == 1) ? Wix : (mat == 2) ? Wfx :
      (mat == 3) ? Wox : (mat == 4) ? Wah : (mat == 5) ? Wih :
      (mat == 6) ? Wfh : Woh;
  unsigned short* D = (mat < 4) ? WxT : WhT;
  int g = mat & 3;
  int tx = threadIdx.x & 31, ty = threadIdx.x >> 5;  // ty in [0,8)
#pragma unroll
  for (int r = 0; r < 4; ++r)
    tile[ty + r * 8][tx] = S[(size_t)(k0 + ty + r * 8) * 512 + h0 + tx];
  __syncthreads();
#pragma unroll
  for (int r = 0; r < 4; ++r) {
    int h = h0 + ty + r * 8;
    int k = k0 + tx;
    D[((size_t)(g * 512 + h) << 9) + k] = f2bf(tile[tx][ty + r * 8]);
  }
}

// X f32 [32768][512] -> bf16
__global__ __launch_bounds__(256) void prep_xbf(const float* __restrict__ X,
                                                unsigned short* __restrict__ Xbf) {
  size_t i = (size_t)blockIdx.x * 256 + threadIdx.x;
  f32x4 v = *(const f32x4*)(X + i * 4);
  short4v o;
  o[0] = (short)f2bf(v[0]); o[1] = (short)f2bf(v[1]);
  o[2] = (short)f2bf(v[2]); o[3] = (short)f2bf(v[3]);
  *(short4v*)(Xbf + i * 4) = o;
}

__global__ __launch_bounds__(256) void prep_bias(
    const float* __restrict__ ba, const float* __restrict__ bi,
    const float* __restrict__ bf, const float* __restrict__ bo,
    float* __restrict__ biascat) {
  int n = blockIdx.x * 256 + threadIdx.x;  // [0,2048)
  int g = n >> 9, h = n & 511;
  const float* s = (g == 0) ? ba : (g == 1) ? bi : (g == 2) ? bf : bo;
  biascat[n] = s[h];
}

// ---------------------------------------------------------------------------
// Fused kernel: 544 blocks x 256 threads.
//   blockIdx >= 32: gemm worker -- 8 tiles of the 4096-tile Xg GEMM,
//     tile id = wkr + 512*k (mt = id>>4 ascending), Xg = Xbf@WxT^T + bias,
//     sc0sc1 stores + ack + xcnt[mt]++.
//   blockIdx < 32: persistent scan (v13), Xg prefetch gated on xcnt.
// ---------------------------------------------------------------------------
__global__ __launch_bounds__(256, 1) void lstm_fused(
    const unsigned short* __restrict__ Xbf,   // [32768][512] bf16
    const unsigned short* __restrict__ WxT,   // [2048][512] bf16
    const float* __restrict__ bcat,           // [2048]
    unsigned short* __restrict__ Xg,          // [2048][64][64][8] bf16
    const unsigned short* __restrict__ WhT,   // [2048][512] bf16
    unsigned short* __restrict__ hbuf,        // [2][64][64][8] bf16 (no init)
    int* __restrict__ flags,                  // [32*32] ints, zeroed
    int* __restrict__ xcnt,                   // [256] ints, zeroed
    float* __restrict__ out) {                // [512][64][512] f32
  __shared__ unsigned short smem[32768];      // 64 KiB, role-dependent use
  const int tid = threadIdx.x;
  const int w = tid >> 6, l = tid & 63;

  if (blockIdx.x >= 32) {
    // ================= GEMM worker role =================
    unsigned short* Asm_ = smem;          // [128*64]
    unsigned short* Bsm_ = smem + 8192;   // [128*64]
    const int wkr = blockIdx.x - 32;      // 0..511
    const int wm = (w >> 1) * 64, wn = (w & 1) * 64;
#pragma unroll 1
    for (int id = wkr; id < 4096; id += 512) {
      const int mt = id >> 4, nt = id & 15;
      const int m0 = mt * 128, n0 = nt * 128;
      f32x4 acc[4][4] = {};
      for (int ks = 0; ks < 8; ++ks) {
        int k0 = ks * 64;
        __syncthreads();
        int lr = l >> 3;
        int ksl = ((l & 7) ^ lr) * 8;
#pragma unroll
        for (int ii = 0; ii < 4; ++ii) {
          int i = w * 4 + ii;
          int r = i * 8 + lr;
          gload_lds16(Xbf + (size_t)(m0 + r) * 512 + k0 + ksl,
                      Asm_ + i * 512 + l * 8);
        }
#pragma unroll
        for (int ii = 0; ii < 4; ++ii) {
          int i = w * 4 + ii;
          int r = i * 8 + lr;
          gload_lds16(WxT + (size_t)(n0 + r) * 512 + k0 + ksl,
                      Bsm_ + i * 512 + l * 8);
        }
        __syncthreads();
#pragma unroll
        for (int kk = 0; kk < 2; ++kk) {
          short8 af[4], bfr[4];
#pragma unroll
          for (int mi = 0; mi < 4; ++mi) {
            int row = wm + mi * 16 + (l & 15);
            int slot = (kk * 4 + (l >> 4)) ^ (row & 7);
            af[mi] = *(const short8*)(Asm_ + row * 64 + slot * 8);
          }
#pragma unroll
          for (int ni = 0; ni < 4; ++ni) {
            int row = wn + ni * 16 + (l & 15);
            int slot = (kk * 4 + (l >> 4)) ^ (row & 7);
            bfr[ni] = *(const short8*)(Bsm_ + row * 64 + slot * 8);
          }
#pragma unroll
          for (int mi = 0; mi < 4; ++mi)
#pragma unroll
            for (int ni = 0; ni < 4; ++ni)
              acc[mi][ni] = __builtin_amdgcn_mfma_f32_16x16x32_bf16(
                  af[mi], bfr[ni], acc[mi][ni], 0, 0, 0);
        }
      }
      // epilogue: sc0sc1 write-through stores (L3-coherent for the scan)
#pragma unroll
      for (int mi = 0; mi < 4; ++mi)
#pragma unroll
        for (int ni = 0; ni < 4; ++ni) {
          int col = n0 + wn + ni * 16 + (l & 15);
          float bias = bcat[col];
          int g = col >> 9, h = col & 511;
          int chunk = h >> 3, e = h & 7;
#pragma unroll
          for (int r = 0; r < 4; ++r) {
            int m = m0 + wm + mi * 16 + (l >> 4) * 4 + r;
            int tt = m >> 6, bb = m & 63;
            unsigned off =
                (unsigned)(((((tt * 4 + g) * 64 + chunk) * 64 + bb) * 8 + e) * 2);
            unsigned val = (unsigned)f2bf(acc[mi][ni][r] + bias);
            asm volatile("global_store_short %0, %1, %2 sc0 sc1"
                         :: "v"(off), "v"(val), "s"(Xg) : "memory");
          }
        }
      asm volatile("s_waitcnt vmcnt(0)" ::: "memory");
      __syncthreads();   // all 4 waves' stores acked at L3
      if (tid == 0)
        __hip_atomic_fetch_add(xcnt + mt, 1, __ATOMIC_RELAXED,
                               __HIP_MEMORY_SCOPE_AGENT);
    }
    return;
  }

  // ================= scan role (v13 protocol) =================
  unsigned short* hsm0 = smem;             // parity 0: 32 KiB
  unsigned short* hsm1 = smem + 16384;     // parity 1: 32 KiB
  const int j = blockIdx.x;   // 0..31
  const int mi = j & 1;
  const int cc = j >> 1;

  // ---- recurrent weights as A-fragments (registers / compiler L2 stream) ----
  short8 wf[32];
  {
    const int m = l & 31;
    const int g = m >> 3;
    const int hcol_w = cc * 32 + w * 8 + (m & 7);
    const unsigned short* base =
        WhT + (((size_t)(g * 512 + hcol_w)) << 9) + (l >> 5) * 8;
#pragma unroll
    for (int kt = 0; kt < 32; ++kt) wf[kt] = *(const short8*)(base + kt * 16);
  }

  const int b = mi * 32 + (l & 31);          // this lane's batch row
  const int half = l >> 5;
  const int hcol0 = cc * 32 + w * 8 + half * 4;  // first of 4 hcols
  const int mychunk = cc * 4 + w;

  // staging: instr (w,i) covers chunks (w*8+i)*2 + half, row mi*32+(l&31)
  const unsigned stg_goff0 = (unsigned)(half * 1024 + (mi * 32 + (l & 31)) * 16);
  // LDS dest byte offset for instr i: (w*8+i)*1024 + l*16
  const int stg_loff0 = w * 8192 + l * 16;
  // bfrag ds_read byte offset: chunk=(kt*2+half), local row l&31
  const int ld_loff0 = half * 512 + (l & 31) * 16;
  // h store voffset (bytes): chunk=mychunk, row b, half
  const unsigned st_voff = (unsigned)(mychunk * 1024 + b * 16 + half * 8);
  // Xg load byte offset base for (tg): (((tg*64+mychunk)*64+b)*8 + half*4)*2
  const unsigned xg_lane_off = (unsigned)(((mychunk * 64 + b) * 8 + half * 4) * 2);

  // per-BLOCK flag, 128B stride: group mi's 16 block-flags on 16 lines
  int* const myflag = flags + (mi * 16 + cc) * 32;
  int* const pollflag = flags + (mi * 16 + (l & 15)) * 32;

  float s4[4] = {0.f, 0.f, 0.f, 0.f};  // cell state, registers, all steps

  // ---- pre-loop: wait for Xg tiles of mt=0 (t=0,1), then load Xg[0] ----
  uint2 xgn[4];
  {
    int cv;
    do {
      cv = __hip_atomic_load(xcnt, __ATOMIC_RELAXED, __HIP_MEMORY_SCOPE_AGENT);
    } while (!__all(cv >= 16));
    asm volatile("" ::: "memory");
#pragma unroll
    for (int g = 0; g < 4; ++g) {
      unsigned off = (unsigned)((0 * 4 + g) * 64 * 64 * 8 * 2) + xg_lane_off;
      asm volatile("global_load_dwordx2 %0, %1, %2 sc0 sc1"
                   : "=v"(xgn[g]) : "v"(off), "s"(Xg));
    }
    asm volatile("s_waitcnt vmcnt(0)" ::: "memory");
    __builtin_amdgcn_sched_barrier(0);
  }

#pragma unroll 1
  for (int t = 0; t < TSTEPS; ++t) {
    f32x16 asum = {};
    uint2 xgn_nx[4];
    const int tn = (t + 1 < TSTEPS) ? t + 1 : TSTEPS - 1;
    if (t > 0) {
      // ---- wait: 16 producer blocks (h) AND Xg tiles for t+1 ----
      const int mtn = tn >> 1;
      int fv, cv;
      do {
        fv = __hip_atomic_load(pollflag, __ATOMIC_RELAXED,
                               __HIP_MEMORY_SCOPE_AGENT);
        cv = __hip_atomic_load(xcnt + mtn, __ATOMIC_RELAXED,
                               __HIP_MEMORY_SCOPE_AGENT);
      } while (!__all((fv >= t) && (cv >= 16)));
      asm volatile("" ::: "memory");
      // ---- cooperative h stage: 8 coherent loads per wave ----
      const unsigned short* hbase = hbuf + (size_t)((t - 1) & 1) * 32768;
      unsigned short* hs = ((t - 1) & 1) ? hsm1 : hsm0;
      short8 tmp[8];
#pragma unroll
      for (int i = 0; i < 8; ++i) {
        asm volatile("global_load_dwordx4 %0, %1, %2 sc0 sc1"
                     : "=v"(tmp[i])
                     : "v"(stg_goff0 + (unsigned)((w * 8 + i) * 2048)),
                       "s"(hbase));
      }
      // ---- Xg prefetch for t+1 (drains under the same vmcnt) ----
#pragma unroll
      for (int g = 0; g < 4; ++g) {
        unsigned off = (unsigned)((tn * 4 + g) * 64 * 64 * 8 * 2) + xg_lane_off;
        asm volatile("global_load_dwordx2 %0, %1, %2 sc0 sc1"
                     : "=v"(xgn_nx[g]) : "v"(off), "s"(Xg));
      }
      asm volatile("s_waitcnt vmcnt(0)" ::: "memory");
      __builtin_amdgcn_sched_barrier(0);
#pragma unroll
      for (int i = 0; i < 8; ++i)
        *(short8*)((char*)hs + stg_loff0 + i * 1024) = tmp[i];
      __syncthreads();  // staging visible to all 4 waves
      // ---- 32 MFMAs, bfrags from LDS ----
      f32x16 a0 = {}, a1 = {};
#pragma unroll
      for (int kt = 0; kt < 32; kt += 2) {
        short8 b0 = *(const short8*)((const char*)hs + ld_loff0 + kt * 1024);
        short8 b1 = *(const short8*)((const char*)hs + ld_loff0 + (kt + 1) * 1024);
        a0 = __builtin_amdgcn_mfma_f32_32x32x16_bf16(wf[kt], b0, a0, 0, 0, 0);
        a1 = __builtin_amdgcn_mfma_f32_32x32x16_bf16(wf[kt + 1], b1, a1,
                                                     0, 0, 0);
      }
      asum = a0 + a1;
    } else {
      // t == 0: prefetch Xg[1] (mt=0 assured by pre-loop poll)
#pragma unroll
      for (int g = 0; g < 4; ++g) {
        unsigned off = (unsigned)((tn * 4 + g) * 64 * 64 * 8 * 2) + xg_lane_off;
        asm volatile("global_load_dwordx2 %0, %1, %2 sc0 sc1"
                     : "=v"(xgn_nx[g]) : "v"(off), "s"(Xg));
      }
      asm volatile("s_waitcnt vmcnt(0)" ::: "memory");
      __builtin_amdgcn_sched_barrier(0);
    }
    // ---- gates: asum[r]: gate g=r>>2, q=r&3 (cols hcol0+q), batch b ----
    float hout[4];
#pragma unroll
    for (int q = 0; q < 4; ++q) {
      float pa = asum[0 * 4 + q] + bf2f((unsigned short)((q < 2 ? xgn[0].x : xgn[0].y) >> ((q & 1) * 16)));
      float pi = asum[1 * 4 + q] + bf2f((unsigned short)((q < 2 ? xgn[1].x : xgn[1].y) >> ((q & 1) * 16)));
      float pf = asum[2 * 4 + q] + bf2f((unsigned short)((q < 2 ? xgn[2].x : xgn[2].y) >> ((q & 1) * 16)));
      float po = asum[3 * 4 + q] + bf2f((unsigned short)((q < 2 ? xgn[3].x : xgn[3].y) >> ((q & 1) * 16)));
      float a  = tanh_fast(pa);
      float ig = sigmoid_fast(pi);
      float fg = sigmoid_fast(pf);
      float og = sigmoid_fast(po);
      s4[q] = a * ig + s4[q] * fg;
      hout[q] = tanh_fast(s4[q]) * og;
    }
    // ---- publish h(t): coalesced 8B sc0sc1 store; block-aggregate flag ----
    {
      unsigned lo = (unsigned)f2bf(hout[0]) | ((unsigned)f2bf(hout[1]) << 16);
      unsigned hi = (unsigned)f2bf(hout[2]) | ((unsigned)f2bf(hout[3]) << 16);
      uint2 hd; hd.x = lo; hd.y = hi;
      const unsigned short* sbase = hbuf + (size_t)(t & 1) * 32768;
      asm volatile("global_store_dwordx2 %0, %1, %2 sc0 sc1"
                   :: "v"(st_voff), "v"(hd), "s"(sbase) : "memory");
      asm volatile("s_waitcnt vmcnt(0)" ::: "memory");
      __syncthreads();  // all 4 waves' h-stores at the coherence point;
                        // also bounds wave skew < 1 step (LDS parity safety)
      if (tid == 0)
        __hip_atomic_store(myflag, t + 1, __ATOMIC_RELAXED,
                           __HIP_MEMORY_SCOPE_AGENT);
    }
    // ---- off critical path: out store; rotate Xg regs ----
    f32x4 ov;
    ov[0] = hout[0]; ov[1] = hout[1]; ov[2] = hout[2]; ov[3] = hout[3];
    *(f32x4*)(out + ((size_t)t * 64 + b) * 512 + hcol0) = ov;
#pragma unroll
    for (int g = 0; g < 4; ++g) xgn[g] = xgn_nx[g];
  }
}

// ---------------------------------------------------------------------------
// Workspace layout (bytes):
//   0          Xg bf16     134217728
//   134217728  Xbf bf16     33554432
//   134217728  hbuf bf16      262144  (overlaps Xbf?? NO -- Xbf is now live
//              during the scan (workers read it). hbuf moved below.)
//   167772160  WxT bf16      2097152
//   169869312  WhT bf16      2097152
//   171966464  biascat f32      8192
//   171974656  flags            4096  (zeroed)
//   171978752  xcnt             1024  (zeroed)
//   171980800  hbuf bf16      262144  (no init; flag-gated)
// ---------------------------------------------------------------------------
extern "C" void kernel_launch(void* const* d_in, const int* in_sizes, int n_in,
                              void* d_out, int out_size, void* d_ws,
                              size_t ws_size, hipStream_t stream) {
  const float* X   = (const float*)d_in[0];
  const float* Wax = (const float*)d_in[1];
  const float* Wix = (const float*)d_in[2];
  const float* Wfx = (const float*)d_in[3];
  const float* Wox = (const float*)d_in[4];
  const float* Wah = (const float*)d_in[5];
  const float* Wih = (const float*)d_in[6];
  const float* Wfh = (const float*)d_in[7];
  const float* Woh = (const float*)d_in[8];
  const float* ba  = (const float*)d_in[9];
  const float* bi  = (const float*)d_in[10];
  const float* bf  = (const float*)d_in[11];
  const float* bo  = (const float*)d_in[12];

  char* ws = (char*)d_ws;
  unsigned short* Xg   = (unsigned short*)(ws);
  unsigned short* Xbf  = (unsigned short*)(ws + 134217728);
  unsigned short* WxT  = (unsigned short*)(ws + 167772160);
  unsigned short* WhT  = (unsigned short*)(ws + 169869312);
  float*          bcat = (float*)(ws + 171966464);
  int*            flags= (int*)(ws + 171974656);
  int*            xcnt = (int*)(ws + 171978752);
  unsigned short* hbuf = (unsigned short*)(ws + 171980800);

  hipMemsetAsync(ws + 171974656, 0, 4096 + 1024, stream);  // flags + xcnt

  prep_wT<<<2048, 256, 0, stream>>>(Wax, Wix, Wfx, Wox, Wah, Wih, Wfh, Woh,
                                    WxT, WhT);
  prep_xbf<<<16384, 256, 0, stream>>>(X, Xbf);
  prep_bias<<<8, 256, 0, stream>>>(ba, bi, bf, bo, bcat);
  lstm_fused<<<544, 256, 0, stream>>>(Xbf, WxT, bcat, Xg, WhT, hbuf, flags,
                                      xcnt, (float*)d_out);
}

// Round 17
// 1857.252 us; speedup vs baseline: 1.0173x; 1.0173x over previous
//
#include <hip/hip_runtime.h>
#include <cmath>

// ---------------------------------------------------------------------------
// LSTM T=512 B=64 I=512 H=512, fp32 in/out, bf16 MFMA compute.
// v17 = v16 fusion with the scan steady state restored to byte-exact v13:
//   - poll = flags only (v16's dual-condition poll cost ~1250cy/step)
//   - xcnt gate amortized via a monotone 'verified' register (zero loads
//     after warmup), placed off-path at the step tail
//   - Xg prefetch = plain cacheable loads in v13's post-publish slot
//     (gated reads: each line read once, only after xcnt ack -> no stale)
// Workers (blocks 32..543) unchanged from v16: 8 tiles each, mt-ascending,
// sc0sc1 stores + vmcnt ack + syncthreads + xcnt[mt]++.
// ---------------------------------------------------------------------------

typedef __attribute__((ext_vector_type(8)))  short   short8;
typedef __attribute__((ext_vector_type(4)))  short   short4v;
typedef __attribute__((ext_vector_type(4)))  float   f32x4;
typedef __attribute__((ext_vector_type(16))) float   f32x16;

#define TSTEPS 512

__device__ __forceinline__ unsigned short f2bf(float f) {
  unsigned u = __builtin_bit_cast(unsigned, f);
  unsigned r = (u + 0x7FFFu + ((u >> 16) & 1u)) >> 16;
  return (unsigned short)r;
}
__device__ __forceinline__ float bf2f(unsigned short s) {
  unsigned u = ((unsigned)s) << 16;
  return __builtin_bit_cast(float, u);
}
__device__ __forceinline__ void gload_lds16(const void* g, void* l) {
  __builtin_amdgcn_global_load_lds(
      (const __attribute__((address_space(1))) unsigned int*)g,
      (__attribute__((address_space(3))) unsigned int*)l, 16, 0, 0);
}
__device__ __forceinline__ float sigmoid_fast(float x) {
  return 1.0f / (1.0f + __expf(-x));
}
__device__ __forceinline__ float tanh_fast(float x) {
  float e = __expf(2.0f * x);
  return 1.0f - 2.0f / (e + 1.0f);
}

// ---------------------------------------------------------------------------
// Prep: transpose+convert weights [512][512] f32 (k-major) -> bf16 [g*512+h][k]
// ---------------------------------------------------------------------------
__global__ __launch_bounds__(256) void prep_wT(
    const float* __restrict__ Wax, const float* __restrict__ Wix,
    const float* __restrict__ Wfx, const float* __restrict__ Wox,
    const float* __restrict__ Wah, const float* __restrict__ Wih,
    const float* __restrict__ Wfh, const float* __restrict__ Woh,
    unsigned short* __restrict__ WxT, unsigned short* __restrict__ WhT) {
  __shared__ float tile[32][33];
  int bx = blockIdx.x;              // 8 mats * 256 tiles
  int mat = bx >> 8;
  int t32 = bx & 255;
  int k0 = (t32 & 15) * 32;
  int h0 = (t32 >> 4) * 32;
  const float* S =
      (mat == 0) ? Wax : (mat == 1) ? Wix : (mat == 2) ? Wfx :
      (mat == 3) ? Wox : (mat == 4) ? Wah : (mat == 5) ? Wih :
      (mat == 6) ? Wfh : Woh;
  unsigned short* D = (mat < 4) ? WxT : WhT;
  int g = mat & 3;
  int tx = threadIdx.x & 31, ty = threadIdx.x >> 5;  // ty in [0,8)
#pragma unroll
  for (int r = 0; r < 4; ++r)
    tile[ty + r * 8][tx] = S[(size_t)(k0 + ty + r * 8) * 512 + h0 + tx];
  __syncthreads();
#pragma unroll
  for (int r = 0; r < 4; ++r) {
    int h = h0 + ty + r * 8;
    int k = k0 + tx;
    D[((size_t)(g * 512 + h) << 9) + k] = f2bf(tile[tx][ty + r * 8]);
  }
}

// X f32 [32768][512] -> bf16
__global__ __launch_bounds__(256) void prep_xbf(const float* __restrict__ X,
                                                unsigned short* __restrict__ Xbf) {
  size_t i = (size_t)blockIdx.x * 256 + threadIdx.x;
  f32x4 v = *(const f32x4*)(X + i * 4);
  short4v o;
  o[0] = (short)f2bf(v[0]); o[1] = (short)f2bf(v[1]);
  o[2] = (short)f2bf(v[2]); o[3] = (short)f2bf(v[3]);
  *(short4v*)(Xbf + i * 4) = o;
}

__global__ __launch_bounds__(256) void prep_bias(
    const float* __restrict__ ba, const float* __restrict__ bi,
    const float* __restrict__ bf, const float* __restrict__ bo,
    float* __restrict__ biascat) {
  int n = blockIdx.x * 256 + threadIdx.x;  // [0,2048)
  int g = n >> 9, h = n & 511;
  const float* s = (g == 0) ? ba : (g == 1) ? bi : (g == 2) ? bf : bo;
  biascat[n] = s[h];
}

// ---------------------------------------------------------------------------
// Fused kernel: 544 blocks x 256 threads.
// ---------------------------------------------------------------------------
__global__ __launch_bounds__(256, 1) void lstm_fused(
    const unsigned short* __restrict__ Xbf,   // [32768][512] bf16
    const unsigned short* __restrict__ WxT,   // [2048][512] bf16
    const float* __restrict__ bcat,           // [2048]
    unsigned short* __restrict__ Xg,          // [2048][64][64][8] bf16
    const unsigned short* __restrict__ WhT,   // [2048][512] bf16
    unsigned short* __restrict__ hbuf,        // [2][64][64][8] bf16 (no init)
    int* __restrict__ flags,                  // [32*32] ints, zeroed
    int* __restrict__ xcnt,                   // [256] ints, zeroed
    float* __restrict__ out) {                // [512][64][512] f32
  __shared__ unsigned short smem[32768];      // 64 KiB, role-dependent use
  const int tid = threadIdx.x;
  const int w = tid >> 6, l = tid & 63;

  if (blockIdx.x >= 32) {
    // ================= GEMM worker role (== v16) =================
    unsigned short* Asm_ = smem;          // [128*64]
    unsigned short* Bsm_ = smem + 8192;   // [128*64]
    const int wkr = blockIdx.x - 32;      // 0..511
    const int wm = (w >> 1) * 64, wn = (w & 1) * 64;
#pragma unroll 1
    for (int id = wkr; id < 4096; id += 512) {
      const int mt = id >> 4, nt = id & 15;
      const int m0 = mt * 128, n0 = nt * 128;
      f32x4 acc[4][4] = {};
      for (int ks = 0; ks < 8; ++ks) {
        int k0 = ks * 64;
        __syncthreads();
        int lr = l >> 3;
        int ksl = ((l & 7) ^ lr) * 8;
#pragma unroll
        for (int ii = 0; ii < 4; ++ii) {
          int i = w * 4 + ii;
          int r = i * 8 + lr;
          gload_lds16(Xbf + (size_t)(m0 + r) * 512 + k0 + ksl,
                      Asm_ + i * 512 + l * 8);
        }
#pragma unroll
        for (int ii = 0; ii < 4; ++ii) {
          int i = w * 4 + ii;
          int r = i * 8 + lr;
          gload_lds16(WxT + (size_t)(n0 + r) * 512 + k0 + ksl,
                      Bsm_ + i * 512 + l * 8);
        }
        __syncthreads();
#pragma unroll
        for (int kk = 0; kk < 2; ++kk) {
          short8 af[4], bfr[4];
#pragma unroll
          for (int mi = 0; mi < 4; ++mi) {
            int row = wm + mi * 16 + (l & 15);
            int slot = (kk * 4 + (l >> 4)) ^ (row & 7);
            af[mi] = *(const short8*)(Asm_ + row * 64 + slot * 8);
          }
#pragma unroll
          for (int ni = 0; ni < 4; ++ni) {
            int row = wn + ni * 16 + (l & 15);
            int slot = (kk * 4 + (l >> 4)) ^ (row & 7);
            bfr[ni] = *(const short8*)(Bsm_ + row * 64 + slot * 8);
          }
#pragma unroll
          for (int mi = 0; mi < 4; ++mi)
#pragma unroll
            for (int ni = 0; ni < 4; ++ni)
              acc[mi][ni] = __builtin_amdgcn_mfma_f32_16x16x32_bf16(
                  af[mi], bfr[ni], acc[mi][ni], 0, 0, 0);
        }
      }
      // epilogue: sc0sc1 write-through stores (L3-coherent for the scan)
#pragma unroll
      for (int mi = 0; mi < 4; ++mi)
#pragma unroll
        for (int ni = 0; ni < 4; ++ni) {
          int col = n0 + wn + ni * 16 + (l & 15);
          float bias = bcat[col];
          int g = col >> 9, h = col & 511;
          int chunk = h >> 3, e = h & 7;
#pragma unroll
          for (int r = 0; r < 4; ++r) {
            int m = m0 + wm + mi * 16 + (l >> 4) * 4 + r;
            int tt = m >> 6, bb = m & 63;
            unsigned off =
                (unsigned)(((((tt * 4 + g) * 64 + chunk) * 64 + bb) * 8 + e) * 2);
            unsigned val = (unsigned)f2bf(acc[mi][ni][r] + bias);
            asm volatile("global_store_short %0, %1, %2 sc0 sc1"
                         :: "v"(off), "v"(val), "s"(Xg) : "memory");
          }
        }
      asm volatile("s_waitcnt vmcnt(0)" ::: "memory");
      __syncthreads();   // all 4 waves' stores acked at L3
      if (tid == 0)
        __hip_atomic_fetch_add(xcnt + mt, 1, __ATOMIC_RELAXED,
                               __HIP_MEMORY_SCOPE_AGENT);
    }
    return;
  }

  // ================= scan role (byte-exact v13 steady state) =================
  unsigned short* hsm0 = smem;             // parity 0: 32 KiB
  unsigned short* hsm1 = smem + 16384;     // parity 1: 32 KiB
  const int j = blockIdx.x;   // 0..31
  const int mi = j & 1;
  const int cc = j >> 1;

  // ---- recurrent weights as A-fragments (registers / compiler L2 stream) ----
  short8 wf[32];
  {
    const int m = l & 31;
    const int g = m >> 3;
    const int hcol_w = cc * 32 + w * 8 + (m & 7);
    const unsigned short* base =
        WhT + (((size_t)(g * 512 + hcol_w)) << 9) + (l >> 5) * 8;
#pragma unroll
    for (int kt = 0; kt < 32; ++kt) wf[kt] = *(const short8*)(base + kt * 16);
  }

  const int b = mi * 32 + (l & 31);          // this lane's batch row
  const int half = l >> 5;
  const int hcol0 = cc * 32 + w * 8 + half * 4;  // first of 4 hcols
  const int mychunk = cc * 4 + w;

  // staging: instr (w,i) covers chunks (w*8+i)*2 + half, row mi*32+(l&31)
  const unsigned stg_goff0 = (unsigned)(half * 1024 + (mi * 32 + (l & 31)) * 16);
  // LDS dest byte offset for instr i: (w*8+i)*1024 + l*16
  const int stg_loff0 = w * 8192 + l * 16;
  // bfrag ds_read byte offset: chunk=(kt*2+half), local row l&31
  const int ld_loff0 = half * 512 + (l & 31) * 16;
  // h store voffset (bytes): chunk=mychunk, row b, half
  const unsigned st_voff = (unsigned)(mychunk * 1024 + b * 16 + half * 8);

  // per-BLOCK flag, 128B stride: group mi's 16 block-flags on 16 lines
  int* const myflag = flags + (mi * 16 + cc) * 32;
  int* const pollflag = flags + (mi * 16 + (l & 15)) * 32;

  float s4[4] = {0.f, 0.f, 0.f, 0.f};  // cell state, registers, all steps

  // ---- pre-loop: wait for all 16 Xg tiles of mt=0, then load Xg[0] ----
  uint2 xgn[4];
  int verified = 0;   // highest mt observed complete (xcnt monotone)
  {
    int cv;
    do {
      cv = __hip_atomic_load(xcnt, __ATOMIC_RELAXED, __HIP_MEMORY_SCOPE_AGENT);
    } while (!__all(cv >= 16));
    asm volatile("" ::: "memory");
#pragma unroll
    for (int g = 0; g < 4; ++g)
      xgn[g] = *(const uint2*)(Xg +
          ((((size_t)(0 * 4 + g) * 64 + mychunk) * 64 + b) * 8 + half * 4));
  }

#pragma unroll 1
  for (int t = 0; t < TSTEPS; ++t) {
    f32x16 asum = {};
    if (t > 0) {
      // ---- wait for all 16 producer blocks of this batch group ----
      int fv;
      do {
        fv = __hip_atomic_load(pollflag, __ATOMIC_RELAXED,
                               __HIP_MEMORY_SCOPE_AGENT);
      } while (!__all(fv >= t));
      asm volatile("" ::: "memory");
      // ---- cooperative stage: 8 coherent loads + 8 ds_writes per wave ----
      const unsigned short* hbase = hbuf + (size_t)((t - 1) & 1) * 32768;
      unsigned short* hs = ((t - 1) & 1) ? hsm1 : hsm0;
      short8 tmp[8];
#pragma unroll
      for (int i = 0; i < 8; ++i) {
        asm volatile("global_load_dwordx4 %0, %1, %2 sc0 sc1"
                     : "=v"(tmp[i])
                     : "v"(stg_goff0 + (unsigned)((w * 8 + i) * 2048)),
                       "s"(hbase));
      }
      asm volatile("s_waitcnt vmcnt(0)" ::: "memory");
      __builtin_amdgcn_sched_barrier(0);
#pragma unroll
      for (int i = 0; i < 8; ++i)
        *(short8*)((char*)hs + stg_loff0 + i * 1024) = tmp[i];
      __syncthreads();  // staging visible to all 4 waves
      // ---- 32 MFMAs, bfrags from LDS (compiler interleaves lgkmcnt) ----
      f32x16 a0 = {}, a1 = {};
#pragma unroll
      for (int kt = 0; kt < 32; kt += 2) {
        short8 b0 = *(const short8*)((const char*)hs + ld_loff0 + kt * 1024);
        short8 b1 = *(const short8*)((const char*)hs + ld_loff0 + (kt + 1) * 1024);
        a0 = __builtin_amdgcn_mfma_f32_32x32x16_bf16(wf[kt], b0, a0, 0, 0, 0);
        a1 = __builtin_amdgcn_mfma_f32_32x32x16_bf16(wf[kt + 1], b1, a1,
                                                     0, 0, 0);
      }
      asum = a0 + a1;
    }
    // ---- gates: asum[r]: gate g=r>>2, q=r&3 (cols hcol0+q), batch b ----
    float hout[4];
#pragma unroll
    for (int q = 0; q < 4; ++q) {
      float pa = asum[0 * 4 + q] + bf2f((unsigned short)((q < 2 ? xgn[0].x : xgn[0].y) >> ((q & 1) * 16)));
      float pi = asum[1 * 4 + q] + bf2f((unsigned short)((q < 2 ? xgn[1].x : xgn[1].y) >> ((q & 1) * 16)));
      float pf = asum[2 * 4 + q] + bf2f((unsigned short)((q < 2 ? xgn[2].x : xgn[2].y) >> ((q & 1) * 16)));
      float po = asum[3 * 4 + q] + bf2f((unsigned short)((q < 2 ? xgn[3].x : xgn[3].y) >> ((q & 1) * 16)));
      float a  = tanh_fast(pa);
      float ig = sigmoid_fast(pi);
      float fg = sigmoid_fast(pf);
      float og = sigmoid_fast(po);
      s4[q] = a * ig + s4[q] * fg;
      hout[q] = tanh_fast(s4[q]) * og;
    }
    // ---- publish h(t): coalesced 8B sc0sc1 store; block-aggregate flag ----
    {
      unsigned lo = (unsigned)f2bf(hout[0]) | ((unsigned)f2bf(hout[1]) << 16);
      unsigned hi = (unsigned)f2bf(hout[2]) | ((unsigned)f2bf(hout[3]) << 16);
      uint2 hd; hd.x = lo; hd.y = hi;
      const unsigned short* sbase = hbuf + (size_t)(t & 1) * 32768;
      asm volatile("global_store_dwordx2 %0, %1, %2 sc0 sc1"
                   :: "v"(st_voff), "v"(hd), "s"(sbase) : "memory");
      asm volatile("s_waitcnt vmcnt(0)" ::: "memory");
      __syncthreads();  // all 4 waves' h-stores at the coherence point;
                        // also bounds wave skew < 1 step (LDS parity safety)
      if (tid == 0)
        __hip_atomic_store(myflag, t + 1, __ATOMIC_RELAXED,
                           __HIP_MEMORY_SCOPE_AGENT);
    }
    // ---- off critical path: out store + gated Xg prefetch (v13 slot) ----
    f32x4 ov;
    ov[0] = hout[0]; ov[1] = hout[1]; ov[2] = hout[2]; ov[3] = hout[3];
    *(f32x4*)(out + ((size_t)t * 64 + b) * 512 + hcol0) = ov;
    const int tn = (t + 1 < TSTEPS) ? t + 1 : TSTEPS - 1;
    const int mtn = tn >> 1;
    if (mtn > verified) {   // warmup only; zero loads afterwards (monotone)
      int cv;
      do {
        cv = __hip_atomic_load(xcnt + mtn, __ATOMIC_RELAXED,
                               __HIP_MEMORY_SCOPE_AGENT);
      } while (!__all(cv >= 16));
      asm volatile("" ::: "memory");
      verified = mtn;
    }
#pragma unroll
    for (int g = 0; g < 4; ++g)
      xgn[g] = *(const uint2*)(Xg +
          ((((size_t)(tn * 4 + g) * 64 + mychunk) * 64 + b) * 8 + half * 4));
  }
}

// ---------------------------------------------------------------------------
// Workspace layout (bytes):
//   0          Xg bf16     134217728
//   134217728  Xbf bf16     33554432  (live during fused kernel)
//   167772160  WxT bf16      2097152
//   169869312  WhT bf16      2097152
//   171966464  biascat f32      8192
//   171974656  flags            4096  (zeroed)
//   171978752  xcnt             1024  (zeroed)
//   171980800  hbuf bf16      262144  (no init; flag-gated)
// ---------------------------------------------------------------------------
extern "C" void kernel_launch(void* const* d_in, const int* in_sizes, int n_in,
                              void* d_out, int out_size, void* d_ws,
                              size_t ws_size, hipStream_t stream) {
  const float* X   = (const float*)d_in[0];
  const float* Wax = (const float*)d_in[1];
  const float* Wix = (const float*)d_in[2];
  const float* Wfx = (const float*)d_in[3];
  const float* Wox = (const float*)d_in[4];
  const float* Wah = (const float*)d_in[5];
  const float* Wih = (const float*)d_in[6];
  const float* Wfh = (const float*)d_in[7];
  const float* Woh = (const float*)d_in[8];
  const float* ba  = (const float*)d_in[9];
  const float* bi  = (const float*)d_in[10];
  const float* bf  = (const float*)d_in[11];
  const float* bo  = (const float*)d_in[12];

  char* ws = (char*)d_ws;
  unsigned short* Xg   = (unsigned short*)(ws);
  unsigned short* Xbf  = (unsigned short*)(ws + 134217728);
  unsigned short* WxT  = (unsigned short*)(ws + 167772160);
  unsigned short* WhT  = (unsigned short*)(ws + 169869312);
  float*          bcat = (float*)(ws + 171966464);
  int*            flags= (int*)(ws + 171974656);
  int*            xcnt = (int*)(ws + 171978752);
  unsigned short* hbuf = (unsigned short*)(ws + 171980800);

  hipMemsetAsync(ws + 171974656, 0, 4096 + 1024, stream);  // flags + xcnt

  prep_wT<<<2048, 256, 0, stream>>>(Wax, Wix, Wfx, Wox, Wah, Wih, Wfh, Woh,
                                    WxT, WhT);
  prep_xbf<<<16384, 256, 0, stream>>>(X, Xbf);
  prep_bias<<<8, 256, 0, stream>>>(ba, bi, bf, bo, bcat);
  lstm_fused<<<544, 256, 0, stream>>>(Xbf, WxT, bcat, Xg, WhT, hbuf, flags,
                                      xcnt, (float*)d_out);
}

// Round 18
// 1762.335 us; speedup vs baseline: 1.0721x; 1.0539x over previous
//
#include <hip/hip_runtime.h>
#include <cmath>

// ---------------------------------------------------------------------------
// LSTM T=512 B=64 I=512 H=512, fp32 in/out, bf16 MFMA compute.
// v18 = v17 fusion, worker-side contention removed (scan untouched):
//   - 256 blocks total (32 scan + 224 workers): one block per CU available,
//     so scan blocks do not share CUs with MFMA/LDS-heavy workers (v17: 544
//     blocks forced co-scheduling).
//   - coalesced Xg epilogue: bf16 tile staged to padded LDS [128][136], then
//     8x global_store_dwordx4 sc0sc1 per thread (16B lane-contiguous) --
//     32x fewer L3 write transactions than v17's per-element 2B stores.
// ---------------------------------------------------------------------------

typedef __attribute__((ext_vector_type(8)))  short   short8;
typedef __attribute__((ext_vector_type(4)))  short   short4v;
typedef __attribute__((ext_vector_type(4)))  float   f32x4;
typedef __attribute__((ext_vector_type(16))) float   f32x16;

#define TSTEPS 512

__device__ __forceinline__ unsigned short f2bf(float f) {
  unsigned u = __builtin_bit_cast(unsigned, f);
  unsigned r = (u + 0x7FFFu + ((u >> 16) & 1u)) >> 16;
  return (unsigned short)r;
}
__device__ __forceinline__ float bf2f(unsigned short s) {
  unsigned u = ((unsigned)s) << 16;
  return __builtin_bit_cast(float, u);
}
__device__ __forceinline__ void gload_lds16(const void* g, void* l) {
  __builtin_amdgcn_global_load_lds(
      (const __attribute__((address_space(1))) unsigned int*)g,
      (__attribute__((address_space(3))) unsigned int*)l, 16, 0, 0);
}
__device__ __forceinline__ float sigmoid_fast(float x) {
  return 1.0f / (1.0f + __expf(-x));
}
__device__ __forceinline__ float tanh_fast(float x) {
  float e = __expf(2.0f * x);
  return 1.0f - 2.0f / (e + 1.0f);
}

// ---------------------------------------------------------------------------
// Prep: transpose+convert weights [512][512] f32 (k-major) -> bf16 [g*512+h][k]
// ---------------------------------------------------------------------------
__global__ __launch_bounds__(256) void prep_wT(
    const float* __restrict__ Wax, const float* __restrict__ Wix,
    const float* __restrict__ Wfx, const float* __restrict__ Wox,
    const float* __restrict__ Wah, const float* __restrict__ Wih,
    const float* __restrict__ Wfh, const float* __restrict__ Woh,
    unsigned short* __restrict__ WxT, unsigned short* __restrict__ WhT) {
  __shared__ float tile[32][33];
  int bx = blockIdx.x;              // 8 mats * 256 tiles
  int mat = bx >> 8;
  int t32 = bx & 255;
  int k0 = (t32 & 15) * 32;
  int h0 = (t32 >> 4) * 32;
  const float* S =
      (mat == 0) ? Wax : (mat == 1) ? Wix : (mat == 2) ? Wfx :
      (mat == 3) ? Wox : (mat == 4) ? Wah : (mat == 5) ? Wih :
      (mat == 6) ? Wfh : Woh;
  unsigned short* D = (mat < 4) ? WxT : WhT;
  int g = mat & 3;
  int tx = threadIdx.x & 31, ty = threadIdx.x >> 5;  // ty in [0,8)
#pragma unroll
  for (int r = 0; r < 4; ++r)
    tile[ty + r * 8][tx] = S[(size_t)(k0 + ty + r * 8) * 512 + h0 + tx];
  __syncthreads();
#pragma unroll
  for (int r = 0; r < 4; ++r) {
    int h = h0 + ty + r * 8;
    int k = k0 + tx;
    D[((size_t)(g * 512 + h) << 9) + k] = f2bf(tile[tx][ty + r * 8]);
  }
}

// X f32 [32768][512] -> bf16
__global__ __launch_bounds__(256) void prep_xbf(const float* __restrict__ X,
                                                unsigned short* __restrict__ Xbf) {
  size_t i = (size_t)blockIdx.x * 256 + threadIdx.x;
  f32x4 v = *(const f32x4*)(X + i * 4);
  short4v o;
  o[0] = (short)f2bf(v[0]); o[1] = (short)f2bf(v[1]);
  o[2] = (short)f2bf(v[2]); o[3] = (short)f2bf(v[3]);
  *(short4v*)(Xbf + i * 4) = o;
}

__global__ __launch_bounds__(256) void prep_bias(
    const float* __restrict__ ba, const float* __restrict__ bi,
    const float* __restrict__ bf, const float* __restrict__ bo,
    float* __restrict__ biascat) {
  int n = blockIdx.x * 256 + threadIdx.x;  // [0,2048)
  int g = n >> 9, h = n & 511;
  const float* s = (g == 0) ? ba : (g == 1) ? bi : (g == 2) ? bf : bo;
  biascat[n] = s[h];
}

// ---------------------------------------------------------------------------
// Fused kernel: 256 blocks x 256 threads (32 scan + 224 gemm workers).
// ---------------------------------------------------------------------------
__global__ __launch_bounds__(256, 1) void lstm_fused(
    const unsigned short* __restrict__ Xbf,   // [32768][512] bf16
    const unsigned short* __restrict__ WxT,   // [2048][512] bf16
    const float* __restrict__ bcat,           // [2048]
    unsigned short* __restrict__ Xg,          // [2048][64][64][8] bf16
    const unsigned short* __restrict__ WhT,   // [2048][512] bf16
    unsigned short* __restrict__ hbuf,        // [2][64][64][8] bf16 (no init)
    int* __restrict__ flags,                  // [32*32] ints, zeroed
    int* __restrict__ xcnt,                   // [256] ints, zeroed
    float* __restrict__ out) {                // [512][64][512] f32
  __shared__ unsigned short smem[33792];      // 66 KiB, role-dependent use
  const int tid = threadIdx.x;
  const int w = tid >> 6, l = tid & 63;

  if (blockIdx.x >= 32) {
    // ================= GEMM worker role =================
    unsigned short* Asm_ = smem;          // 8192 shorts
    unsigned short* Bsm_ = smem + 8192;   // 8192 shorts
    unsigned short* tbuf = smem + 16384;  // 128 x 136 shorts (padded tile)
    const int wkr = blockIdx.x - 32;      // 0..223
    const int wm = (w >> 1) * 64, wn = (w & 1) * 64;
#pragma unroll 1
    for (int id = wkr; id < 4096; id += 224) {
      const int mt = id >> 4, nt = id & 15;
      const int m0 = mt * 128, n0 = nt * 128;
      f32x4 acc[4][4] = {};
      for (int ks = 0; ks < 8; ++ks) {
        int k0 = ks * 64;
        __syncthreads();
        int lr = l >> 3;
        int ksl = ((l & 7) ^ lr) * 8;
#pragma unroll
        for (int ii = 0; ii < 4; ++ii) {
          int i = w * 4 + ii;
          int r = i * 8 + lr;
          gload_lds16(Xbf + (size_t)(m0 + r) * 512 + k0 + ksl,
                      Asm_ + i * 512 + l * 8);
        }
#pragma unroll
        for (int ii = 0; ii < 4; ++ii) {
          int i = w * 4 + ii;
          int r = i * 8 + lr;
          gload_lds16(WxT + (size_t)(n0 + r) * 512 + k0 + ksl,
                      Bsm_ + i * 512 + l * 8);
        }
        __syncthreads();
#pragma unroll
        for (int kk = 0; kk < 2; ++kk) {
          short8 af[4], bfr[4];
#pragma unroll
          for (int mi = 0; mi < 4; ++mi) {
            int row = wm + mi * 16 + (l & 15);
            int slot = (kk * 4 + (l >> 4)) ^ (row & 7);
            af[mi] = *(const short8*)(Asm_ + row * 64 + slot * 8);
          }
#pragma unroll
          for (int ni = 0; ni < 4; ++ni) {
            int row = wn + ni * 16 + (l & 15);
            int slot = (kk * 4 + (l >> 4)) ^ (row & 7);
            bfr[ni] = *(const short8*)(Bsm_ + row * 64 + slot * 8);
          }
#pragma unroll
          for (int mi = 0; mi < 4; ++mi)
#pragma unroll
            for (int ni = 0; ni < 4; ++ni)
              acc[mi][ni] = __builtin_amdgcn_mfma_f32_16x16x32_bf16(
                  af[mi], bfr[ni], acc[mi][ni], 0, 0, 0);
        }
      }
      // ---- epilogue: bias + bf16 -> padded LDS tile, then coalesced
      //      16B sc0sc1 stores (lane-contiguous over b) ----
#pragma unroll
      for (int mi = 0; mi < 4; ++mi)
#pragma unroll
        for (int ni = 0; ni < 4; ++ni) {
          int c = wn + ni * 16 + (l & 15);
          float bias = bcat[n0 + c];
#pragma unroll
          for (int r = 0; r < 4; ++r) {
            int m = wm + mi * 16 + (l >> 4) * 4 + r;
            tbuf[m * 136 + c] = f2bf(acc[mi][ni][r] + bias);
          }
        }
      __syncthreads();   // tile staged
      {
        const int g = nt >> 2;
        const int cb = (nt & 3) * 16;
#pragma unroll
        for (int u = 0; u < 8; ++u) {
          int unit = u * 256 + tid;          // [t_i:1][chunk_i:4][b_i:6]... 2048 units
          int t_i = unit >> 10;
          int chunk_i = (unit >> 6) & 15;
          int b_i = unit & 63;
          short8 v = *(const short8*)(tbuf + (t_i * 64 + b_i) * 136 + chunk_i * 8);
          unsigned off = (unsigned)(((((mt * 2 + t_i) * 4 + g) * 64 +
                                      (cb + chunk_i)) * 64 + b_i) * 16);
          asm volatile("global_store_dwordx4 %0, %1, %2 sc0 sc1"
                       :: "v"(off), "v"(v), "s"(Xg) : "memory");
        }
      }
      asm volatile("s_waitcnt vmcnt(0)" ::: "memory");
      __syncthreads();   // all stores acked at L3; also guards tbuf reuse
      if (tid == 0)
        __hip_atomic_fetch_add(xcnt + mt, 1, __ATOMIC_RELAXED,
                               __HIP_MEMORY_SCOPE_AGENT);
    }
    return;
  }

  // ================= scan role (byte-exact v13 steady state) =================
  unsigned short* hsm0 = smem;             // parity 0: 32 KiB
  unsigned short* hsm1 = smem + 16384;     // parity 1: 32 KiB
  const int j = blockIdx.x;   // 0..31
  const int mi = j & 1;
  const int cc = j >> 1;

  // ---- recurrent weights as A-fragments (registers / compiler L2 stream) ----
  short8 wf[32];
  {
    const int m = l & 31;
    const int g = m >> 3;
    const int hcol_w = cc * 32 + w * 8 + (m & 7);
    const unsigned short* base =
        WhT + (((size_t)(g * 512 + hcol_w)) << 9) + (l >> 5) * 8;
#pragma unroll
    for (int kt = 0; kt < 32; ++kt) wf[kt] = *(const short8*)(base + kt * 16);
  }

  const int b = mi * 32 + (l & 31);          // this lane's batch row
  const int half = l >> 5;
  const int hcol0 = cc * 32 + w * 8 + half * 4;  // first of 4 hcols
  const int mychunk = cc * 4 + w;

  // staging: instr (w,i) covers chunks (w*8+i)*2 + half, row mi*32+(l&31)
  const unsigned stg_goff0 = (unsigned)(half * 1024 + (mi * 32 + (l & 31)) * 16);
  // LDS dest byte offset for instr i: (w*8+i)*1024 + l*16
  const int stg_loff0 = w * 8192 + l * 16;
  // bfrag ds_read byte offset: chunk=(kt*2+half), local row l&31
  const int ld_loff0 = half * 512 + (l & 31) * 16;
  // h store voffset (bytes): chunk=mychunk, row b, half
  const unsigned st_voff = (unsigned)(mychunk * 1024 + b * 16 + half * 8);

  // per-BLOCK flag, 128B stride: group mi's 16 block-flags on 16 lines
  int* const myflag = flags + (mi * 16 + cc) * 32;
  int* const pollflag = flags + (mi * 16 + (l & 15)) * 32;

  float s4[4] = {0.f, 0.f, 0.f, 0.f};  // cell state, registers, all steps

  // ---- pre-loop: wait for all 16 Xg tiles of mt=0, then load Xg[0] ----
  uint2 xgn[4];
  int verified = 0;   // highest mt observed complete (xcnt monotone)
  {
    int cv;
    do {
      cv = __hip_atomic_load(xcnt, __ATOMIC_RELAXED, __HIP_MEMORY_SCOPE_AGENT);
    } while (!__all(cv >= 16));
    asm volatile("" ::: "memory");
#pragma unroll
    for (int g = 0; g < 4; ++g)
      xgn[g] = *(const uint2*)(Xg +
          ((((size_t)(0 * 4 + g) * 64 + mychunk) * 64 + b) * 8 + half * 4));
  }

#pragma unroll 1
  for (int t = 0; t < TSTEPS; ++t) {
    f32x16 asum = {};
    if (t > 0) {
      // ---- wait for all 16 producer blocks of this batch group ----
      int fv;
      do {
        fv = __hip_atomic_load(pollflag, __ATOMIC_RELAXED,
                               __HIP_MEMORY_SCOPE_AGENT);
      } while (!__all(fv >= t));
      asm volatile("" ::: "memory");
      // ---- cooperative stage: 8 coherent loads + 8 ds_writes per wave ----
      const unsigned short* hbase = hbuf + (size_t)((t - 1) & 1) * 32768;
      unsigned short* hs = ((t - 1) & 1) ? hsm1 : hsm0;
      short8 tmp[8];
#pragma unroll
      for (int i = 0; i < 8; ++i) {
        asm volatile("global_load_dwordx4 %0, %1, %2 sc0 sc1"
                     : "=v"(tmp[i])
                     : "v"(stg_goff0 + (unsigned)((w * 8 + i) * 2048)),
                       "s"(hbase));
      }
      asm volatile("s_waitcnt vmcnt(0)" ::: "memory");
      __builtin_amdgcn_sched_barrier(0);
#pragma unroll
      for (int i = 0; i < 8; ++i)
        *(short8*)((char*)hs + stg_loff0 + i * 1024) = tmp[i];
      __syncthreads();  // staging visible to all 4 waves
      // ---- 32 MFMAs, bfrags from LDS (compiler interleaves lgkmcnt) ----
      f32x16 a0 = {}, a1 = {};
#pragma unroll
      for (int kt = 0; kt < 32; kt += 2) {
        short8 b0 = *(const short8*)((const char*)hs + ld_loff0 + kt * 1024);
        short8 b1 = *(const short8*)((const char*)hs + ld_loff0 + (kt + 1) * 1024);
        a0 = __builtin_amdgcn_mfma_f32_32x32x16_bf16(wf[kt], b0, a0, 0, 0, 0);
        a1 = __builtin_amdgcn_mfma_f32_32x32x16_bf16(wf[kt + 1], b1, a1,
                                                     0, 0, 0);
      }
      asum = a0 + a1;
    }
    // ---- gates: asum[r]: gate g=r>>2, q=r&3 (cols hcol0+q), batch b ----
    float hout[4];
#pragma unroll
    for (int q = 0; q < 4; ++q) {
      float pa = asum[0 * 4 + q] + bf2f((unsigned short)((q < 2 ? xgn[0].x : xgn[0].y) >> ((q & 1) * 16)));
      float pi = asum[1 * 4 + q] + bf2f((unsigned short)((q < 2 ? xgn[1].x : xgn[1].y) >> ((q & 1) * 16)));
      float pf = asum[2 * 4 + q] + bf2f((unsigned short)((q < 2 ? xgn[2].x : xgn[2].y) >> ((q & 1) * 16)));
      float po = asum[3 * 4 + q] + bf2f((unsigned short)((q < 2 ? xgn[3].x : xgn[3].y) >> ((q & 1) * 16)));
      float a  = tanh_fast(pa);
      float ig = sigmoid_fast(pi);
      float fg = sigmoid_fast(pf);
      float og = sigmoid_fast(po);
      s4[q] = a * ig + s4[q] * fg;
      hout[q] = tanh_fast(s4[q]) * og;
    }
    // ---- publish h(t): coalesced 8B sc0sc1 store; block-aggregate flag ----
    {
      unsigned lo = (unsigned)f2bf(hout[0]) | ((unsigned)f2bf(hout[1]) << 16);
      unsigned hi = (unsigned)f2bf(hout[2]) | ((unsigned)f2bf(hout[3]) << 16);
      uint2 hd; hd.x = lo; hd.y = hi;
      const unsigned short* sbase = hbuf + (size_t)(t & 1) * 32768;
      asm volatile("global_store_dwordx2 %0, %1, %2 sc0 sc1"
                   :: "v"(st_voff), "v"(hd), "s"(sbase) : "memory");
      asm volatile("s_waitcnt vmcnt(0)" ::: "memory");
      __syncthreads();  // all 4 waves' h-stores at the coherence point;
                        // also bounds wave skew < 1 step (LDS parity safety)
      if (tid == 0)
        __hip_atomic_store(myflag, t + 1, __ATOMIC_RELAXED,
                           __HIP_MEMORY_SCOPE_AGENT);
    }
    // ---- off critical path: out store + gated Xg prefetch (v13 slot) ----
    f32x4 ov;
    ov[0] = hout[0]; ov[1] = hout[1]; ov[2] = hout[2]; ov[3] = hout[3];
    *(f32x4*)(out + ((size_t)t * 64 + b) * 512 + hcol0) = ov;
    const int tn = (t + 1 < TSTEPS) ? t + 1 : TSTEPS - 1;
    const int mtn = tn >> 1;
    if (mtn > verified) {   // warmup only; zero loads afterwards (monotone)
      int cv;
      do {
        cv = __hip_atomic_load(xcnt + mtn, __ATOMIC_RELAXED,
                               __HIP_MEMORY_SCOPE_AGENT);
      } while (!__all(cv >= 16));
      asm volatile("" ::: "memory");
      verified = mtn;
    }
#pragma unroll
    for (int g = 0; g < 4; ++g)
      xgn[g] = *(const uint2*)(Xg +
          ((((size_t)(tn * 4 + g) * 64 + mychunk) * 64 + b) * 8 + half * 4));
  }
}

// ---------------------------------------------------------------------------
// Workspace layout (bytes):
//   0          Xg bf16     134217728
//   134217728  Xbf bf16     33554432  (live during fused kernel)
//   167772160  WxT bf16      2097152
//   169869312  WhT bf16      2097152
//   171966464  biascat f32      8192
//   171974656  flags            4096  (zeroed)
//   171978752  xcnt             1024  (zeroed)
//   171980800  hbuf bf16      262144  (no init; flag-gated)
// ---------------------------------------------------------------------------
extern "C" void kernel_launch(void* const* d_in, const int* in_sizes, int n_in,
                              void* d_out, int out_size, void* d_ws,
                              size_t ws_size, hipStream_t stream) {
  const float* X   = (const float*)d_in[0];
  const float* Wax = (const float*)d_in[1];
  const float* Wix = (const float*)d_in[2];
  const float* Wfx = (const float*)d_in[3];
  const float* Wox = (const float*)d_in[4];
  const float* Wah = (const float*)d_in[5];
  const float* Wih = (const float*)d_in[6];
  const float* Wfh = (const float*)d_in[7];
  const float* Woh = (const float*)d_in[8];
  const float* ba  = (const float*)d_in[9];
  const float* bi  = (const float*)d_in[10];
  const float* bf  = (const float*)d_in[11];
  const float* bo  = (const float*)d_in[12];

  char* ws = (char*)d_ws;
  unsigned short* Xg   = (unsigned short*)(ws);
  unsigned short* Xbf  = (unsigned short*)(ws + 134217728);
  unsigned short* WxT  = (unsigned short*)(ws + 167772160);
  unsigned short* WhT  = (unsigned short*)(ws + 169869312);
  float*          bcat = (float*)(ws + 171966464);
  int*            flags= (int*)(ws + 171974656);
  int*            xcnt = (int*)(ws + 171978752);
  unsigned short* hbuf = (unsigned short*)(ws + 171980800);

  hipMemsetAsync(ws + 171974656, 0, 4096 + 1024, stream);  // flags + xcnt

  prep_wT<<<2048, 256, 0, stream>>>(Wax, Wix, Wfx, Wox, Wah, Wih, Wfh, Woh,
                                    WxT, WhT);
  prep_xbf<<<16384, 256, 0, stream>>>(X, Xbf);
  prep_bias<<<8, 256, 0, stream>>>(ba, bi, bf, bo, bcat);
  lstm_fused<<<256, 256, 0, stream>>>(Xbf, WxT, bcat, Xg, WhT, hbuf, flags,
                                      xcnt, (float*)d_out);
}

// Round 19
// 1736.200 us; speedup vs baseline: 1.0883x; 1.0151x over previous
//
#include <hip/hip_runtime.h>
#include <cmath>

// ---------------------------------------------------------------------------
// LSTM T=512 B=64 I=512 H=512, fp32 in/out, bf16 MFMA compute.
// v19 = v18, single diff: two-phase worker schedule.
//   Phase 1: ids 0..511 (mt 0..31) stride-224 -- early mts ready fast.
//   Phase 2: worker w owns mt=32+w entirely (16 consecutive nt) -- A-tile
//   read from L3 once, reused 16x in L1/L2. Cuts the workers' L3 read
//   traffic ~5x during the overlap window that contends with the scan's
//   handoff RTTs. Scan role byte-identical to v18 (v13 protocol).
// ---------------------------------------------------------------------------

typedef __attribute__((ext_vector_type(8)))  short   short8;
typedef __attribute__((ext_vector_type(4)))  short   short4v;
typedef __attribute__((ext_vector_type(4)))  float   f32x4;
typedef __attribute__((ext_vector_type(16))) float   f32x16;

#define TSTEPS 512

__device__ __forceinline__ unsigned short f2bf(float f) {
  unsigned u = __builtin_bit_cast(unsigned, f);
  unsigned r = (u + 0x7FFFu + ((u >> 16) & 1u)) >> 16;
  return (unsigned short)r;
}
__device__ __forceinline__ float bf2f(unsigned short s) {
  unsigned u = ((unsigned)s) << 16;
  return __builtin_bit_cast(float, u);
}
__device__ __forceinline__ void gload_lds16(const void* g, void* l) {
  __builtin_amdgcn_global_load_lds(
      (const __attribute__((address_space(1))) unsigned int*)g,
      (__attribute__((address_space(3))) unsigned int*)l, 16, 0, 0);
}
__device__ __forceinline__ float sigmoid_fast(float x) {
  return 1.0f / (1.0f + __expf(-x));
}
__device__ __forceinline__ float tanh_fast(float x) {
  float e = __expf(2.0f * x);
  return 1.0f - 2.0f / (e + 1.0f);
}

// ---------------------------------------------------------------------------
// Prep: transpose+convert weights [512][512] f32 (k-major) -> bf16 [g*512+h][k]
// ---------------------------------------------------------------------------
__global__ __launch_bounds__(256) void prep_wT(
    const float* __restrict__ Wax, const float* __restrict__ Wix,
    const float* __restrict__ Wfx, const float* __restrict__ Wox,
    const float* __restrict__ Wah, const float* __restrict__ Wih,
    const float* __restrict__ Wfh, const float* __restrict__ Woh,
    unsigned short* __restrict__ WxT, unsigned short* __restrict__ WhT) {
  __shared__ float tile[32][33];
  int bx = blockIdx.x;              // 8 mats * 256 tiles
  int mat = bx >> 8;
  int t32 = bx & 255;
  int k0 = (t32 & 15) * 32;
  int h0 = (t32 >> 4) * 32;
  const float* S =
      (mat == 0) ? Wax : (mat == 1) ? Wix : (mat == 2) ? Wfx :
      (mat == 3) ? Wox : (mat == 4) ? Wah : (mat == 5) ? Wih :
      (mat == 6) ? Wfh : Woh;
  unsigned short* D = (mat < 4) ? WxT : WhT;
  int g = mat & 3;
  int tx = threadIdx.x & 31, ty = threadIdx.x >> 5;  // ty in [0,8)
#pragma unroll
  for (int r = 0; r < 4; ++r)
    tile[ty + r * 8][tx] = S[(size_t)(k0 + ty + r * 8) * 512 + h0 + tx];
  __syncthreads();
#pragma unroll
  for (int r = 0; r < 4; ++r) {
    int h = h0 + ty + r * 8;
    int k = k0 + tx;
    D[((size_t)(g * 512 + h) << 9) + k] = f2bf(tile[tx][ty + r * 8]);
  }
}

// X f32 [32768][512] -> bf16
__global__ __launch_bounds__(256) void prep_xbf(const float* __restrict__ X,
                                                unsigned short* __restrict__ Xbf) {
  size_t i = (size_t)blockIdx.x * 256 + threadIdx.x;
  f32x4 v = *(const f32x4*)(X + i * 4);
  short4v o;
  o[0] = (short)f2bf(v[0]); o[1] = (short)f2bf(v[1]);
  o[2] = (short)f2bf(v[2]); o[3] = (short)f2bf(v[3]);
  *(short4v*)(Xbf + i * 4) = o;
}

__global__ __launch_bounds__(256) void prep_bias(
    const float* __restrict__ ba, const float* __restrict__ bi,
    const float* __restrict__ bf, const float* __restrict__ bo,
    float* __restrict__ biascat) {
  int n = blockIdx.x * 256 + threadIdx.x;  // [0,2048)
  int g = n >> 9, h = n & 511;
  const float* s = (g == 0) ? ba : (g == 1) ? bi : (g == 2) ? bf : bo;
  biascat[n] = s[h];
}

// ---------------------------------------------------------------------------
// Fused kernel: 256 blocks x 256 threads (32 scan + 224 gemm workers).
// ---------------------------------------------------------------------------
__global__ __launch_bounds__(256, 1) void lstm_fused(
    const unsigned short* __restrict__ Xbf,   // [32768][512] bf16
    const unsigned short* __restrict__ WxT,   // [2048][512] bf16
    const float* __restrict__ bcat,           // [2048]
    unsigned short* __restrict__ Xg,          // [2048][64][64][8] bf16
    const unsigned short* __restrict__ WhT,   // [2048][512] bf16
    unsigned short* __restrict__ hbuf,        // [2][64][64][8] bf16 (no init)
    int* __restrict__ flags,                  // [32*32] ints, zeroed
    int* __restrict__ xcnt,                   // [256] ints, zeroed
    float* __restrict__ out) {                // [512][64][512] f32
  __shared__ unsigned short smem[33792];      // 66 KiB, role-dependent use
  const int tid = threadIdx.x;
  const int w = tid >> 6, l = tid & 63;

  if (blockIdx.x >= 32) {
    // ================= GEMM worker role =================
    unsigned short* Asm_ = smem;          // 8192 shorts
    unsigned short* Bsm_ = smem + 8192;   // 8192 shorts
    unsigned short* tbuf = smem + 16384;  // 128 x 136 shorts (padded tile)
    const int wkr = blockIdx.x - 32;      // 0..223
    const int wm = (w >> 1) * 64, wn = (w & 1) * 64;

    auto do_tile = [&](int mt, int nt) {
      const int m0 = mt * 128, n0 = nt * 128;
      f32x4 acc[4][4] = {};
      for (int ks = 0; ks < 8; ++ks) {
        int k0 = ks * 64;
        __syncthreads();
        int lr = l >> 3;
        int ksl = ((l & 7) ^ lr) * 8;
#pragma unroll
        for (int ii = 0; ii < 4; ++ii) {
          int i = w * 4 + ii;
          int r = i * 8 + lr;
          gload_lds16(Xbf + (size_t)(m0 + r) * 512 + k0 + ksl,
                      Asm_ + i * 512 + l * 8);
        }
#pragma unroll
        for (int ii = 0; ii < 4; ++ii) {
          int i = w * 4 + ii;
          int r = i * 8 + lr;
          gload_lds16(WxT + (size_t)(n0 + r) * 512 + k0 + ksl,
                      Bsm_ + i * 512 + l * 8);
        }
        __syncthreads();
#pragma unroll
        for (int kk = 0; kk < 2; ++kk) {
          short8 af[4], bfr[4];
#pragma unroll
          for (int mi = 0; mi < 4; ++mi) {
            int row = wm + mi * 16 + (l & 15);
            int slot = (kk * 4 + (l >> 4)) ^ (row & 7);
            af[mi] = *(const short8*)(Asm_ + row * 64 + slot * 8);
          }
#pragma unroll
          for (int ni = 0; ni < 4; ++ni) {
            int row = wn + ni * 16 + (l & 15);
            int slot = (kk * 4 + (l >> 4)) ^ (row & 7);
            bfr[ni] = *(const short8*)(Bsm_ + row * 64 + slot * 8);
          }
#pragma unroll
          for (int mi = 0; mi < 4; ++mi)
#pragma unroll
            for (int ni = 0; ni < 4; ++ni)
              acc[mi][ni] = __builtin_amdgcn_mfma_f32_16x16x32_bf16(
                  af[mi], bfr[ni], acc[mi][ni], 0, 0, 0);
        }
      }
      // ---- epilogue: bias + bf16 -> padded LDS tile, then coalesced
      //      16B sc0sc1 stores (lane-contiguous over b) ----
#pragma unroll
      for (int mi = 0; mi < 4; ++mi)
#pragma unroll
        for (int ni = 0; ni < 4; ++ni) {
          int c = wn + ni * 16 + (l & 15);
          float bias = bcat[n0 + c];
#pragma unroll
          for (int r = 0; r < 4; ++r) {
            int m = wm + mi * 16 + (l >> 4) * 4 + r;
            tbuf[m * 136 + c] = f2bf(acc[mi][ni][r] + bias);
          }
        }
      __syncthreads();   // tile staged
      {
        const int g = nt >> 2;
        const int cb = (nt & 3) * 16;
#pragma unroll
        for (int u = 0; u < 8; ++u) {
          int unit = u * 256 + tid;          // 2048 units of 16B
          int t_i = unit >> 10;
          int chunk_i = (unit >> 6) & 15;
          int b_i = unit & 63;
          short8 v = *(const short8*)(tbuf + (t_i * 64 + b_i) * 136 + chunk_i * 8);
          unsigned off = (unsigned)(((((mt * 2 + t_i) * 4 + g) * 64 +
                                      (cb + chunk_i)) * 64 + b_i) * 16);
          asm volatile("global_store_dwordx4 %0, %1, %2 sc0 sc1"
                       :: "v"(off), "v"(v), "s"(Xg) : "memory");
        }
      }
      asm volatile("s_waitcnt vmcnt(0)" ::: "memory");
      __syncthreads();   // all stores acked at L3; also guards tbuf reuse
      if (tid == 0)
        __hip_atomic_fetch_add(xcnt + mt, 1, __ATOMIC_RELAXED,
                               __HIP_MEMORY_SCOPE_AGENT);
    };

    // Phase 1: mt 0..31 (ids 0..511), stride-224 -- early mts ready fast.
#pragma unroll 1
    for (int id = wkr; id < 512; id += 224) do_tile(id >> 4, id & 15);
    // Phase 2: worker w owns mt = 32 + w entirely (A-tile reused 16x).
    {
      const int mt2 = 32 + wkr;
      if (mt2 < 256) {
#pragma unroll 1
        for (int nt = 0; nt < 16; ++nt) do_tile(mt2, nt);
      }
    }
    return;
  }

  // ================= scan role (byte-exact v13 steady state) =================
  unsigned short* hsm0 = smem;             // parity 0: 32 KiB
  unsigned short* hsm1 = smem + 16384;     // parity 1: 32 KiB
  const int j = blockIdx.x;   // 0..31
  const int mi = j & 1;
  const int cc = j >> 1;

  // ---- recurrent weights as A-fragments (registers / compiler L2 stream) ----
  short8 wf[32];
  {
    const int m = l & 31;
    const int g = m >> 3;
    const int hcol_w = cc * 32 + w * 8 + (m & 7);
    const unsigned short* base =
        WhT + (((size_t)(g * 512 + hcol_w)) << 9) + (l >> 5) * 8;
#pragma unroll
    for (int kt = 0; kt < 32; ++kt) wf[kt] = *(const short8*)(base + kt * 16);
  }

  const int b = mi * 32 + (l & 31);          // this lane's batch row
  const int half = l >> 5;
  const int hcol0 = cc * 32 + w * 8 + half * 4;  // first of 4 hcols
  const int mychunk = cc * 4 + w;

  // staging: instr (w,i) covers chunks (w*8+i)*2 + half, row mi*32+(l&31)
  const unsigned stg_goff0 = (unsigned)(half * 1024 + (mi * 32 + (l & 31)) * 16);
  // LDS dest byte offset for instr i: (w*8+i)*1024 + l*16
  const int stg_loff0 = w * 8192 + l * 16;
  // bfrag ds_read byte offset: chunk=(kt*2+half), local row l&31
  const int ld_loff0 = half * 512 + (l & 31) * 16;
  // h store voffset (bytes): chunk=mychunk, row b, half
  const unsigned st_voff = (unsigned)(mychunk * 1024 + b * 16 + half * 8);

  // per-BLOCK flag, 128B stride: group mi's 16 block-flags on 16 lines
  int* const myflag = flags + (mi * 16 + cc) * 32;
  int* const pollflag = flags + (mi * 16 + (l & 15)) * 32;

  float s4[4] = {0.f, 0.f, 0.f, 0.f};  // cell state, registers, all steps

  // ---- pre-loop: wait for all 16 Xg tiles of mt=0, then load Xg[0] ----
  uint2 xgn[4];
  int verified = 0;   // highest mt observed complete (xcnt monotone)
  {
    int cv;
    do {
      cv = __hip_atomic_load(xcnt, __ATOMIC_RELAXED, __HIP_MEMORY_SCOPE_AGENT);
    } while (!__all(cv >= 16));
    asm volatile("" ::: "memory");
#pragma unroll
    for (int g = 0; g < 4; ++g)
      xgn[g] = *(const uint2*)(Xg +
          ((((size_t)(0 * 4 + g) * 64 + mychunk) * 64 + b) * 8 + half * 4));
  }

#pragma unroll 1
  for (int t = 0; t < TSTEPS; ++t) {
    f32x16 asum = {};
    if (t > 0) {
      // ---- wait for all 16 producer blocks of this batch group ----
      int fv;
      do {
        fv = __hip_atomic_load(pollflag, __ATOMIC_RELAXED,
                               __HIP_MEMORY_SCOPE_AGENT);
      } while (!__all(fv >= t));
      asm volatile("" ::: "memory");
      // ---- cooperative stage: 8 coherent loads + 8 ds_writes per wave ----
      const unsigned short* hbase = hbuf + (size_t)((t - 1) & 1) * 32768;
      unsigned short* hs = ((t - 1) & 1) ? hsm1 : hsm0;
      short8 tmp[8];
#pragma unroll
      for (int i = 0; i < 8; ++i) {
        asm volatile("global_load_dwordx4 %0, %1, %2 sc0 sc1"
                     : "=v"(tmp[i])
                     : "v"(stg_goff0 + (unsigned)((w * 8 + i) * 2048)),
                       "s"(hbase));
      }
      asm volatile("s_waitcnt vmcnt(0)" ::: "memory");
      __builtin_amdgcn_sched_barrier(0);
#pragma unroll
      for (int i = 0; i < 8; ++i)
        *(short8*)((char*)hs + stg_loff0 + i * 1024) = tmp[i];
      __syncthreads();  // staging visible to all 4 waves
      // ---- 32 MFMAs, bfrags from LDS (compiler interleaves lgkmcnt) ----
      f32x16 a0 = {}, a1 = {};
#pragma unroll
      for (int kt = 0; kt < 32; kt += 2) {
        short8 b0 = *(const short8*)((const char*)hs + ld_loff0 + kt * 1024);
        short8 b1 = *(const short8*)((const char*)hs + ld_loff0 + (kt + 1) * 1024);
        a0 = __builtin_amdgcn_mfma_f32_32x32x16_bf16(wf[kt], b0, a0, 0, 0, 0);
        a1 = __builtin_amdgcn_mfma_f32_32x32x16_bf16(wf[kt + 1], b1, a1,
                                                     0, 0, 0);
      }
      asum = a0 + a1;
    }
    // ---- gates: asum[r]: gate g=r>>2, q=r&3 (cols hcol0+q), batch b ----
    float hout[4];
#pragma unroll
    for (int q = 0; q < 4; ++q) {
      float pa = asum[0 * 4 + q] + bf2f((unsigned short)((q < 2 ? xgn[0].x : xgn[0].y) >> ((q & 1) * 16)));
      float pi = asum[1 * 4 + q] + bf2f((unsigned short)((q < 2 ? xgn[1].x : xgn[1].y) >> ((q & 1) * 16)));
      float pf = asum[2 * 4 + q] + bf2f((unsigned short)((q < 2 ? xgn[2].x : xgn[2].y) >> ((q & 1) * 16)));
      float po = asum[3 * 4 + q] + bf2f((unsigned short)((q < 2 ? xgn[3].x : xgn[3].y) >> ((q & 1) * 16)));
      float a  = tanh_fast(pa);
      float ig = sigmoid_fast(pi);
      float fg = sigmoid_fast(pf);
      float og = sigmoid_fast(po);
      s4[q] = a * ig + s4[q] * fg;
      hout[q] = tanh_fast(s4[q]) * og;
    }
    // ---- publish h(t): coalesced 8B sc0sc1 store; block-aggregate flag ----
    {
      unsigned lo = (unsigned)f2bf(hout[0]) | ((unsigned)f2bf(hout[1]) << 16);
      unsigned hi = (unsigned)f2bf(hout[2]) | ((unsigned)f2bf(hout[3]) << 16);
      uint2 hd; hd.x = lo; hd.y = hi;
      const unsigned short* sbase = hbuf + (size_t)(t & 1) * 32768;
      asm volatile("global_store_dwordx2 %0, %1, %2 sc0 sc1"
                   :: "v"(st_voff), "v"(hd), "s"(sbase) : "memory");
      asm volatile("s_waitcnt vmcnt(0)" ::: "memory");
      __syncthreads();  // all 4 waves' h-stores at the coherence point;
                        // also bounds wave skew < 1 step (LDS parity safety)
      if (tid == 0)
        __hip_atomic_store(myflag, t + 1, __ATOMIC_RELAXED,
                           __HIP_MEMORY_SCOPE_AGENT);
    }
    // ---- off critical path: out store + gated Xg prefetch (v13 slot) ----
    f32x4 ov;
    ov[0] = hout[0]; ov[1] = hout[1]; ov[2] = hout[2]; ov[3] = hout[3];
    *(f32x4*)(out + ((size_t)t * 64 + b) * 512 + hcol0) = ov;
    const int tn = (t + 1 < TSTEPS) ? t + 1 : TSTEPS - 1;
    const int mtn = tn >> 1;
    if (mtn > verified) {   // warmup only; zero loads afterwards (monotone)
      int cv;
      do {
        cv = __hip_atomic_load(xcnt + mtn, __ATOMIC_RELAXED,
                               __HIP_MEMORY_SCOPE_AGENT);
      } while (!__all(cv >= 16));
      asm volatile("" ::: "memory");
      verified = mtn;
    }
#pragma unroll
    for (int g = 0; g < 4; ++g)
      xgn[g] = *(const uint2*)(Xg +
          ((((size_t)(tn * 4 + g) * 64 + mychunk) * 64 + b) * 8 + half * 4));
  }
}

// ---------------------------------------------------------------------------
// Workspace layout (bytes):
//   0          Xg bf16     134217728
//   134217728  Xbf bf16     33554432  (live during fused kernel)
//   167772160  WxT bf16      2097152
//   169869312  WhT bf16      2097152
//   171966464  biascat f32      8192
//   171974656  flags            4096  (zeroed)
//   171978752  xcnt             1024  (zeroed)
//   171980800  hbuf bf16      262144  (no init; flag-gated)
// ---------------------------------------------------------------------------
extern "C" void kernel_launch(void* const* d_in, const int* in_sizes, int n_in,
                              void* d_out, int out_size, void* d_ws,
                              size_t ws_size, hipStream_t stream) {
  const float* X   = (const float*)d_in[0];
  const float* Wax = (const float*)d_in[1];
  const float* Wix = (const float*)d_in[2];
  const float* Wfx = (const float*)d_in[3];
  const float* Wox = (const float*)d_in[4];
  const float* Wah = (const float*)d_in[5];
  const float* Wih = (const float*)d_in[6];
  const float* Wfh = (const float*)d_in[7];
  const float* Woh = (const float*)d_in[8];
  const float* ba  = (const float*)d_in[9];
  const float* bi  = (const float*)d_in[10];
  const float* bf  = (const float*)d_in[11];
  const float* bo  = (const float*)d_in[12];

  char* ws = (char*)d_ws;
  unsigned short* Xg   = (unsigned short*)(ws);
  unsigned short* Xbf  = (unsigned short*)(ws + 134217728);
  unsigned short* WxT  = (unsigned short*)(ws + 167772160);
  unsigned short* WhT  = (unsigned short*)(ws + 169869312);
  float*          bcat = (float*)(ws + 171966464);
  int*            flags= (int*)(ws + 171974656);
  int*            xcnt = (int*)(ws + 171978752);
  unsigned short* hbuf = (unsigned short*)(ws + 171980800);

  hipMemsetAsync(ws + 171974656, 0, 4096 + 1024, stream);  // flags + xcnt

  prep_wT<<<2048, 256, 0, stream>>>(Wax, Wix, Wfx, Wox, Wah, Wih, Wfh, Woh,
                                    WxT, WhT);
  prep_xbf<<<16384, 256, 0, stream>>>(X, Xbf);
  prep_bias<<<8, 256, 0, stream>>>(ba, bi, bf, bo, bcat);
  lstm_fused<<<256, 256, 0, stream>>>(Xbf, WxT, bcat, Xg, WhT, hbuf, flags,
                                      xcnt, (float*)d_out);
}